// Round 3
// baseline (252.719 us; speedup 1.0000x reference)
//
#include <hip/hip_runtime.h>

// Splice: out[m][j] = a[m/R][j]      for j <  sa
//                   = b[m][j - sa]   for sa <= j < sa+sb
//                   = dst[m][j]      for j >= sa+sb
//
// Structure: one block per ROW, 256 threads, M=2048 blocks
//   (= 8 blocks/CU x 256 CU: exactly one resident cohort, no launch tail).
//
// XCD swizzle: block bid -> row m = (bid%8)*(M/8) + bid/8, so each XCD
//   (round-robin bid%8) owns a CONTIGUOUS 256-row chunk. The 4 sibling
//   rows sharing an a_row land on the SAME XCD -> a_row is read once into
//   that XCD's L2 and reused 4x locally (active a-footprint per XCD:
//   64 rows x 64 KB = 4 MB = L2 size). dst/out traffic is nontemporal so
//   the single-use 203 MB stream doesn't evict the reused a rows.
//
// Row split into 3 uniform loops (pure-A / pure-tail / tiny mixed scalar),
// copy loops unrolled x8 for deep load batching.

typedef int v4i __attribute__((ext_vector_type(4)));

__global__ __launch_bounds__(256) void splice_kernel(
    const int* __restrict__ dst,
    const int* __restrict__ a,
    const int* __restrict__ b,
    const int* __restrict__ seq_a,
    const int* __restrict__ seq_b,
    int* __restrict__ out,
    int LEN_OUT, int LEN_A, int LEN_B, int repeat_shift, int M)
{
    const int bid = blockIdx.x;
    // XCD-contiguous row mapping (bijective when M % 8 == 0)
    const int m = ((M & 7) == 0) ? ((bid & 7) * (M >> 3) + (bid >> 3)) : bid;
    const int tid = threadIdx.x;

    const int ia    = m >> repeat_shift;
    const int sa    = seq_a[ia];            // block-uniform -> scalar load
    const int sb    = seq_b[m];             // block-uniform -> scalar load
    const int total = sa + sb;

    const int NV = LEN_OUT >> 2;            // int4s per row (4128)
    const int nA = sa >> 2;                 // int4s fully inside A
    const int nT = (total + 3) >> 2;        // first int4 fully inside tail

    const int* a_row = a   + (size_t)ia * LEN_A;
    const int* d_row = dst + (size_t)m  * LEN_OUT;
    const int* b_row = b   + (size_t)m  * LEN_B;
    int*       o_row = out + (size_t)m  * LEN_OUT;

    const v4i* a4 = (const v4i*)a_row;
    const v4i* d4 = (const v4i*)d_row;
    v4i*       o4 = (v4i*)o_row;

    // ---- A region: cached loads (reused 4x within this XCD's L2),
    //      streaming stores ----
#pragma unroll 8
    for (int vc = tid; vc < nA; vc += 256) {
        v4i v = a4[vc];
        __builtin_nontemporal_store(v, &o4[vc]);
    }

    // ---- tail region: pure streaming copy dst -> out ----
#pragma unroll 8
    for (int vc = nT + tid; vc < NV; vc += 256) {
        v4i v = __builtin_nontemporal_load(&d4[vc]);
        __builtin_nontemporal_store(v, &o4[vc]);
    }

    // ---- mixed region [nA, nT): <= ~34 int4s per row, scalar ----
    for (int vc = nA + tid; vc < nT; vc += 256) {
        const int j0 = vc << 2;
        v4i v;
#pragma unroll
        for (int k = 0; k < 4; ++k) {
            const int j = j0 + k;
            int val;
            if (j < sa)         val = a_row[j];
            else if (j < total) val = b_row[j - sa];
            else                val = d_row[j];
            v[k] = val;
        }
        __builtin_nontemporal_store(v, &o4[vc]);
    }
}

extern "C" void kernel_launch(void* const* d_in, const int* in_sizes, int n_in,
                              void* d_out, int out_size, void* d_ws, size_t ws_size,
                              hipStream_t stream) {
    const int* dst   = (const int*)d_in[0];  // (M, LEN_OUT)
    const int* a     = (const int*)d_in[1];  // (BS, LEN_A)
    const int* b     = (const int*)d_in[2];  // (M, LEN_B)
    const int* seq_a = (const int*)d_in[3];  // (BS,)
    const int* seq_b = (const int*)d_in[4];  // (M,)
    int* out = (int*)d_out;

    const int BS      = in_sizes[3];          // 512
    const int M       = in_sizes[4];          // 2048
    const int LEN_A   = in_sizes[1] / BS;     // 16384
    const int LEN_B   = in_sizes[2] / M;      // 128
    const int LEN_OUT = in_sizes[0] / M;      // 16512
    const int repeat  = M / BS;               // 4
    int repeat_shift = 0;
    while ((1 << repeat_shift) < repeat) ++repeat_shift;

    dim3 block(256);
    dim3 grid(M);                             // one block per row
    splice_kernel<<<grid, block, 0, stream>>>(dst, a, b, seq_a, seq_b, out,
                                              LEN_OUT, LEN_A, LEN_B,
                                              repeat_shift, M);
}